// Round 1
// baseline (83.934 us; speedup 1.0000x reference)
//
#include <hip/hip_runtime.h>

#define N_QUBITS 4
#define N_LAYERS 6
#define NSTATES  16   // 2^N_QUBITS

// complex helpers on float2
__device__ __forceinline__ float2 cmul(float2 a, float2 b) {
    return make_float2(a.x * b.x - a.y * b.y, a.x * b.y + a.y * b.x);
}
__device__ __forceinline__ float2 cadd(float2 a, float2 b) {
    return make_float2(a.x + b.x, a.y + b.y);
}

__global__ __launch_bounds__(256) void qc_kernel(
        const float* __restrict__ inputs,     // (B, 4)
        const float* __restrict__ weights,    // (6, 4, 3)
        float* __restrict__ out,              // (B, 4)
        int B) {
    // Rot matrices are batch-uniform: compute once per block into LDS.
    __shared__ float2 rotm[N_LAYERS][N_QUBITS][4];

    const int t = threadIdx.x;
    if (t < N_LAYERS * N_QUBITS) {
        const int l = t / N_QUBITS, w = t % N_QUBITS;
        const float phi   = weights[(l * N_QUBITS + w) * 3 + 0];
        const float theta = weights[(l * N_QUBITS + w) * 3 + 1];
        const float omega = weights[(l * N_QUBITS + w) * 3 + 2];
        float st, ct;
        sincosf(theta * 0.5f, &st, &ct);
        // m00 = e^{-i(phi+omega)/2} c ; m01 = -e^{+i(phi-omega)/2} s
        // m10 = e^{-i(phi-omega)/2} s ; m11 = e^{+i(phi+omega)/2} c
        const float a1 = -(phi + omega) * 0.5f;
        const float a2 =  (phi - omega) * 0.5f;
        float s1, c1, s2, c2;
        sincosf(a1, &s1, &c1);
        sincosf(a2, &s2, &c2);
        rotm[l][w][0] = make_float2( c1 * ct,  s1 * ct);
        rotm[l][w][1] = make_float2(-c2 * st, -s2 * st);
        rotm[l][w][2] = make_float2( c2 * st, -s2 * st);   // e^{-i a2} = (c2, -s2)
        rotm[l][w][3] = make_float2( c1 * ct, -s1 * ct);   // conj of m00's phase
    }
    __syncthreads();

    const int b = blockIdx.x * blockDim.x + t;
    if (b >= B) return;

    // --- AngleEmbedding RY on |0000>: closed-form product state (real) ---
    const float4 xin = reinterpret_cast<const float4*>(inputs)[b];
    float cc[N_QUBITS], ss[N_QUBITS];
    sincosf(xin.x * 0.5f, &ss[0], &cc[0]);
    sincosf(xin.y * 0.5f, &ss[1], &cc[1]);
    sincosf(xin.z * 0.5f, &ss[2], &cc[2]);
    sincosf(xin.w * 0.5f, &ss[3], &cc[3]);

    float2 amp[NSTATES];
    #pragma unroll
    for (int i = 0; i < NSTATES; ++i) {
        // wire w <-> bit (3-w); bit=1 -> sin component
        float v = 1.0f;
        #pragma unroll
        for (int w = 0; w < N_QUBITS; ++w)
            v *= ((i >> (3 - w)) & 1) ? ss[w] : cc[w];
        amp[i] = make_float2(v, 0.0f);
    }

    // --- StronglyEntanglingLayers, fully unrolled ---
    #pragma unroll
    for (int l = 0; l < N_LAYERS; ++l) {
        #pragma unroll
        for (int w = 0; w < N_QUBITS; ++w) {
            const int bit = 1 << (3 - w);
            const float2 m00 = rotm[l][w][0];
            const float2 m01 = rotm[l][w][1];
            const float2 m10 = rotm[l][w][2];
            const float2 m11 = rotm[l][w][3];
            #pragma unroll
            for (int i = 0; i < NSTATES; ++i) {
                if (!(i & bit)) {
                    const int j = i | bit;
                    const float2 a0 = amp[i];
                    const float2 a1v = amp[j];
                    amp[i] = cadd(cmul(m00, a0), cmul(m01, a1v));
                    amp[j] = cadd(cmul(m10, a0), cmul(m11, a1v));
                }
            }
        }
        const int r = l % (N_QUBITS - 1) + 1;
        #pragma unroll
        for (int w = 0; w < N_QUBITS; ++w) {
            const int cbit = 1 << (3 - w);
            const int tbit = 1 << (3 - ((w + r) % N_QUBITS));
            #pragma unroll
            for (int i = 0; i < NSTATES; ++i) {
                if ((i & cbit) && !(i & tbit)) {
                    const int j = i | tbit;
                    const float2 tmp = amp[i];
                    amp[i] = amp[j];
                    amp[j] = tmp;
                }
            }
        }
    }

    // --- <Z_w> ---
    float z0 = 0.f, z1 = 0.f, z2 = 0.f, z3 = 0.f;
    #pragma unroll
    for (int i = 0; i < NSTATES; ++i) {
        const float p = amp[i].x * amp[i].x + amp[i].y * amp[i].y;
        z0 += ((i >> 3) & 1) ? -p : p;
        z1 += ((i >> 2) & 1) ? -p : p;
        z2 += ((i >> 1) & 1) ? -p : p;
        z3 += ((i >> 0) & 1) ? -p : p;
    }
    reinterpret_cast<float4*>(out)[b] = make_float4(z0, z1, z2, z3);
}

extern "C" void kernel_launch(void* const* d_in, const int* in_sizes, int n_in,
                              void* d_out, int out_size, void* d_ws, size_t ws_size,
                              hipStream_t stream) {
    const float* inputs  = (const float*)d_in[0];   // (B, 4) float32
    const float* weights = (const float*)d_in[1];   // (6, 4, 3) float32
    float* out = (float*)d_out;                     // (B, 4) float32
    const int B = in_sizes[0] / N_QUBITS;
    const int block = 256;
    const int grid = (B + block - 1) / block;
    qc_kernel<<<grid, block, 0, stream>>>(inputs, weights, out, B);
}

// Round 2
// 72.998 us; speedup vs baseline: 1.1498x; 1.1498x over previous
//
#include <hip/hip_runtime.h>

#define N_QUBITS 4
#define N_LAYERS 6
#define NSTATES  16   // 2^N_QUBITS

__device__ __forceinline__ float2 cmul(float2 a, float2 b) {
    return make_float2(a.x * b.x - a.y * b.y, a.x * b.y + a.y * b.x);
}
__device__ __forceinline__ float2 cadd(float2 a, float2 b) {
    return make_float2(a.x + b.x, a.y + b.y);
}

// ---------------------------------------------------------------------------
// Pre-kernel: build the batch-uniform 16x16 circuit unitary U into d_ws.
// One block, 64 threads. Threads 0..23 build the Rot matrices; threads 0..15
// then each simulate one basis-state column through the 6 entangling layers.
// U stored row-major as interleaved re/im: U[2*(i*16+k)], U[2*(i*16+k)+1].
// ---------------------------------------------------------------------------
__global__ void build_u_kernel(const float* __restrict__ weights,
                               float* __restrict__ U) {
    __shared__ float2 rotm[N_LAYERS][N_QUBITS][4];

    const int t = threadIdx.x;
    if (t < N_LAYERS * N_QUBITS) {
        const int l = t / N_QUBITS, w = t % N_QUBITS;
        const float phi   = weights[(l * N_QUBITS + w) * 3 + 0];
        const float theta = weights[(l * N_QUBITS + w) * 3 + 1];
        const float omega = weights[(l * N_QUBITS + w) * 3 + 2];
        float st, ct;
        sincosf(theta * 0.5f, &st, &ct);
        const float a1 = -(phi + omega) * 0.5f;
        const float a2 =  (phi - omega) * 0.5f;
        float s1, c1, s2, c2;
        sincosf(a1, &s1, &c1);
        sincosf(a2, &s2, &c2);
        rotm[l][w][0] = make_float2( c1 * ct,  s1 * ct);   // m00
        rotm[l][w][1] = make_float2(-c2 * st, -s2 * st);   // m01
        rotm[l][w][2] = make_float2( c2 * st, -s2 * st);   // m10
        rotm[l][w][3] = make_float2( c1 * ct, -s1 * ct);   // m11
    }
    __syncthreads();

    if (t < NSTATES) {
        float2 amp[NSTATES];
        #pragma unroll
        for (int i = 0; i < NSTATES; ++i)
            amp[i] = make_float2(i == t ? 1.0f : 0.0f, 0.0f);

        #pragma unroll
        for (int l = 0; l < N_LAYERS; ++l) {
            #pragma unroll
            for (int w = 0; w < N_QUBITS; ++w) {
                const int bit = 1 << (3 - w);
                const float2 m00 = rotm[l][w][0];
                const float2 m01 = rotm[l][w][1];
                const float2 m10 = rotm[l][w][2];
                const float2 m11 = rotm[l][w][3];
                #pragma unroll
                for (int i = 0; i < NSTATES; ++i) {
                    if (!(i & bit)) {
                        const int j = i | bit;
                        const float2 a0 = amp[i];
                        const float2 a1v = amp[j];
                        amp[i] = cadd(cmul(m00, a0), cmul(m01, a1v));
                        amp[j] = cadd(cmul(m10, a0), cmul(m11, a1v));
                    }
                }
            }
            const int r = l % (N_QUBITS - 1) + 1;
            #pragma unroll
            for (int w = 0; w < N_QUBITS; ++w) {
                const int cbit = 1 << (3 - w);
                const int tbit = 1 << (3 - ((w + r) % N_QUBITS));
                #pragma unroll
                for (int i = 0; i < NSTATES; ++i) {
                    if ((i & cbit) && !(i & tbit)) {
                        const int j = i | tbit;
                        const float2 tmp = amp[i];
                        amp[i] = amp[j];
                        amp[j] = tmp;
                    }
                }
            }
        }

        // column t of U: U[i][t] = amp[i]
        #pragma unroll
        for (int i = 0; i < NSTATES; ++i) {
            U[2 * (i * NSTATES + t) + 0] = amp[i].x;
            U[2 * (i * NSTATES + t) + 1] = amp[i].y;
        }
    }
}

// ---------------------------------------------------------------------------
// Main kernel: per sample, v = RY-product state (real, rank-1 over qubits);
// amp = U @ v (complex 16x16 times real 16-vector); z_w via sign butterfly.
// U is uniform -> scalar (SGPR) loads, no LDS.
// ---------------------------------------------------------------------------
__global__ __launch_bounds__(256) void qc_apply_kernel(
        const float* __restrict__ inputs,   // (B, 4)
        const float* __restrict__ U,        // 16x16 complex, interleaved
        float* __restrict__ out,            // (B, 4)
        int B) {
    const int b = blockIdx.x * blockDim.x + threadIdx.x;
    if (b >= B) return;

    const float4 xin = reinterpret_cast<const float4*>(inputs)[b];
    float s0, c0, s1, c1, s2, c2, s3, c3;
    __sincosf(xin.x * 0.5f, &s0, &c0);
    __sincosf(xin.y * 0.5f, &s1, &c1);
    __sincosf(xin.z * 0.5f, &s2, &c2);
    __sincosf(xin.w * 0.5f, &s3, &c3);

    // v[i], i bits (b3 b2 b1 b0) = (wire0, wire1, wire2, wire3); bit=1 -> sin
    float vA[4] = { c0 * c1, c0 * s1, s0 * c1, s0 * s1 };  // wires 0,1
    float vB[4] = { c2 * c3, c2 * s3, s2 * c3, s2 * s3 };  // wires 2,3
    float v[NSTATES];
    #pragma unroll
    for (int a = 0; a < 4; ++a)
        #pragma unroll
        for (int q = 0; q < 4; ++q)
            v[a * 4 + q] = vA[a] * vB[q];

    float p[NSTATES];
    #pragma unroll
    for (int i = 0; i < NSTATES; ++i) {
        float re = 0.0f, im = 0.0f;
        #pragma unroll
        for (int k = 0; k < NSTATES; ++k) {
            const float ur = U[2 * (i * NSTATES + k) + 0];
            const float ui = U[2 * (i * NSTATES + k) + 1];
            re = fmaf(ur, v[k], re);
            im = fmaf(ui, v[k], im);
        }
        p[i] = re * re + im * im;
    }

    // Sign butterfly: z_w = sum_i (1 - 2*bit_{3-w}(i)) * p[i]
    float s0a[8], d0a[8];
    #pragma unroll
    for (int j = 0; j < 8; ++j) {
        s0a[j] = p[2 * j] + p[2 * j + 1];
        d0a[j] = p[2 * j] - p[2 * j + 1];
    }
    float z3 = ((d0a[0] + d0a[1]) + (d0a[2] + d0a[3])) +
               ((d0a[4] + d0a[5]) + (d0a[6] + d0a[7]));
    float s1a[4], d1a[4];
    #pragma unroll
    for (int j = 0; j < 4; ++j) {
        s1a[j] = s0a[2 * j] + s0a[2 * j + 1];
        d1a[j] = s0a[2 * j] - s0a[2 * j + 1];
    }
    float z2 = (d1a[0] + d1a[1]) + (d1a[2] + d1a[3]);
    float s2a0 = s1a[0] + s1a[1], s2a1 = s1a[2] + s1a[3];
    float d2a0 = s1a[0] - s1a[1], d2a1 = s1a[2] - s1a[3];
    float z1 = d2a0 + d2a1;
    float z0 = s2a0 - s2a1;

    reinterpret_cast<float4*>(out)[b] = make_float4(z0, z1, z2, z3);
}

extern "C" void kernel_launch(void* const* d_in, const int* in_sizes, int n_in,
                              void* d_out, int out_size, void* d_ws, size_t ws_size,
                              hipStream_t stream) {
    const float* inputs  = (const float*)d_in[0];   // (B, 4) float32
    const float* weights = (const float*)d_in[1];   // (6, 4, 3) float32
    float* out = (float*)d_out;                     // (B, 4) float32
    float* U   = (float*)d_ws;                      // 512 floats scratch
    const int B = in_sizes[0] / N_QUBITS;

    build_u_kernel<<<1, 64, 0, stream>>>(weights, U);

    const int block = 256;
    const int grid = (B + block - 1) / block;
    qc_apply_kernel<<<grid, block, 0, stream>>>(inputs, U, out, B);
}

// Round 3
// 68.982 us; speedup vs baseline: 1.2167x; 1.0582x over previous
//
#include <hip/hip_runtime.h>

#define N_QUBITS 4
#define N_LAYERS 6
#define NSTATES  16   // 2^N_QUBITS

__device__ __forceinline__ float2 cmul(float2 a, float2 b) {
    return make_float2(a.x * b.x - a.y * b.y, a.x * b.y + a.y * b.x);
}
__device__ __forceinline__ float2 cadd(float2 a, float2 b) {
    return make_float2(a.x + b.x, a.y + b.y);
}

// ---------------------------------------------------------------------------
// Pre-kernel: build the batch-uniform 16x16 circuit unitary U into d_ws.
// ONE block, 256 threads = 16 columns x 16 states. State lives in LDS, gate
// loops stay ROLLED (tiny code, low VGPR) — the previous fully-unrolled
// per-thread version spilled and ran 86 us on one cold wave.
// U row-major interleaved re/im: U[2*(i*16+k)+{0,1}] = <i|U|k>.
// ---------------------------------------------------------------------------
__global__ __launch_bounds__(256) void build_u_kernel(
        const float* __restrict__ weights, float* __restrict__ U) {
    __shared__ float2 rotm[N_LAYERS * N_QUBITS][4];
    __shared__ float2 st[NSTATES][NSTATES];   // [column k][state i]

    const int t = threadIdx.x;
    if (t < N_LAYERS * N_QUBITS) {
        const float phi   = weights[t * 3 + 0];
        const float theta = weights[t * 3 + 1];
        const float omega = weights[t * 3 + 2];
        float stheta, ctheta;
        sincosf(theta * 0.5f, &stheta, &ctheta);
        const float a1 = -(phi + omega) * 0.5f;
        const float a2 =  (phi - omega) * 0.5f;
        float s1, c1, s2, c2;
        sincosf(a1, &s1, &c1);
        sincosf(a2, &s2, &c2);
        rotm[t][0] = make_float2( c1 * ctheta,  s1 * ctheta);   // m00
        rotm[t][1] = make_float2(-c2 * stheta, -s2 * stheta);   // m01
        rotm[t][2] = make_float2( c2 * stheta, -s2 * stheta);   // m10
        rotm[t][3] = make_float2( c1 * ctheta, -s1 * ctheta);   // m11
    }

    const int c = t >> 4;     // column (input basis state)
    const int i = t & 15;     // state index within the column's vector
    st[c][i] = make_float2(i == c ? 1.0f : 0.0f, 0.0f);
    __syncthreads();

    #pragma unroll 1
    for (int l = 0; l < N_LAYERS; ++l) {
        // --- Rot gates on each wire ---
        #pragma unroll 1
        for (int w = 0; w < N_QUBITS; ++w) {
            const int bit = 8 >> w;
            if (!(i & bit)) {
                const int j = i | bit;
                const float2 a0 = st[c][i];
                const float2 a1v = st[c][j];
                const float2 m00 = rotm[l * N_QUBITS + w][0];
                const float2 m01 = rotm[l * N_QUBITS + w][1];
                const float2 m10 = rotm[l * N_QUBITS + w][2];
                const float2 m11 = rotm[l * N_QUBITS + w][3];
                st[c][i] = cadd(cmul(m00, a0), cmul(m01, a1v));
                st[c][j] = cadd(cmul(m10, a0), cmul(m11, a1v));
            }
            __syncthreads();
        }
        // --- ring of CNOTs, range r: basis-label permutation ---
        const int r = l % (N_QUBITS - 1) + 1;
        int fi = i;
        #pragma unroll
        for (int w = 0; w < N_QUBITS; ++w) {
            const int tb = 8 >> ((w + r) & 3);
            if ((fi >> (3 - w)) & 1) fi ^= tb;   // CNOT: target ^= control
        }
        const float2 a = st[c][i];
        __syncthreads();
        st[c][fi] = a;
        __syncthreads();
    }

    // U[i][c] = st[c][i]
    U[2 * (i * NSTATES + c) + 0] = st[c][i].x;
    U[2 * (i * NSTATES + c) + 1] = st[c][i].y;
}

// ---------------------------------------------------------------------------
// Main kernel: v = RY product state (real), amp = U @ v, z via sign butterfly.
// U rows are 128 B contiguous -> float4 loads (uniform across the wave, L1).
// ---------------------------------------------------------------------------
__global__ __launch_bounds__(256) void qc_apply_kernel(
        const float* __restrict__ inputs,   // (B, 4)
        const float* __restrict__ U,        // 16x16 complex, interleaved
        float* __restrict__ out,            // (B, 4)
        int B) {
    const int b = blockIdx.x * blockDim.x + threadIdx.x;
    if (b >= B) return;

    const float4 xin = reinterpret_cast<const float4*>(inputs)[b];
    float s0, c0, s1, c1, s2, c2, s3, c3;
    __sincosf(xin.x * 0.5f, &s0, &c0);
    __sincosf(xin.y * 0.5f, &s1, &c1);
    __sincosf(xin.z * 0.5f, &s2, &c2);
    __sincosf(xin.w * 0.5f, &s3, &c3);

    // v[i], i bits (b3 b2 b1 b0) = wires (0,1,2,3); bit=1 -> sin
    const float vA[4] = { c0 * c1, c0 * s1, s0 * c1, s0 * s1 };  // wires 0,1
    const float vB[4] = { c2 * c3, c2 * s3, s2 * c3, s2 * s3 };  // wires 2,3
    float v[NSTATES];
    #pragma unroll
    for (int a = 0; a < 4; ++a)
        #pragma unroll
        for (int q = 0; q < 4; ++q)
            v[a * 4 + q] = vA[a] * vB[q];

    float p[NSTATES];
    #pragma unroll
    for (int i = 0; i < NSTATES; ++i) {
        const float4* row = reinterpret_cast<const float4*>(U + 2 * NSTATES * i);
        float re = 0.0f, im = 0.0f;
        #pragma unroll
        for (int q = 0; q < 8; ++q) {          // 8 float4 = 16 complex entries
            const float4 u4 = row[q];
            re = fmaf(u4.x, v[2 * q],     re);
            im = fmaf(u4.y, v[2 * q],     im);
            re = fmaf(u4.z, v[2 * q + 1], re);
            im = fmaf(u4.w, v[2 * q + 1], im);
        }
        p[i] = re * re + im * im;
    }

    // Sign butterfly: z_w = sum_i (1 - 2*bit_{3-w}(i)) * p[i]
    float sa[8], da[8];
    #pragma unroll
    for (int j = 0; j < 8; ++j) {
        sa[j] = p[2 * j] + p[2 * j + 1];
        da[j] = p[2 * j] - p[2 * j + 1];
    }
    const float z3 = ((da[0] + da[1]) + (da[2] + da[3])) +
                     ((da[4] + da[5]) + (da[6] + da[7]));
    float sb[4], db[4];
    #pragma unroll
    for (int j = 0; j < 4; ++j) {
        sb[j] = sa[2 * j] + sa[2 * j + 1];
        db[j] = sa[2 * j] - sa[2 * j + 1];
    }
    const float z2 = (db[0] + db[1]) + (db[2] + db[3]);
    const float z1 = (sb[0] - sb[1]) + (sb[2] - sb[3]);
    const float z0 = (sb[0] + sb[1]) - (sb[2] + sb[3]);

    reinterpret_cast<float4*>(out)[b] = make_float4(z0, z1, z2, z3);
}

extern "C" void kernel_launch(void* const* d_in, const int* in_sizes, int n_in,
                              void* d_out, int out_size, void* d_ws, size_t ws_size,
                              hipStream_t stream) {
    const float* inputs  = (const float*)d_in[0];   // (B, 4) float32
    const float* weights = (const float*)d_in[1];   // (6, 4, 3) float32
    float* out = (float*)d_out;                     // (B, 4) float32
    float* U   = (float*)d_ws;                      // 512 floats scratch
    const int B = in_sizes[0] / N_QUBITS;

    build_u_kernel<<<1, 256, 0, stream>>>(weights, U);

    const int block = 256;
    const int grid = (B + block - 1) / block;
    qc_apply_kernel<<<grid, block, 0, stream>>>(inputs, U, out, B);
}